// Round 3
// baseline (489.209 us; speedup 1.0000x reference)
//
#include <hip/hip_runtime.h>
#include <hip/hip_bf16.h>

#define SEQ 2048
#define DIMM 2048
#define NQH 32
#define NKVH 8
#define HD 64

typedef _Float16 half8 __attribute__((ext_vector_type(8)));
typedef float f32x4 __attribute__((ext_vector_type(4)));
using fp16 = _Float16;

// ---------------- split fp32 -> fp16 hi + fp16 lo (vectorized) ----------------
__global__ void split_f32_f16(const float* __restrict__ in, fp16* __restrict__ hi,
                              fp16* __restrict__ lo, int n) {
    int i = (blockIdx.x * 256 + threadIdx.x) * 4;
    if (i < n) {
        float4 v = *reinterpret_cast<const float4*>(in + i);
#pragma unroll
        for (int j = 0; j < 4; j++) {
            float f = (&v.x)[j];
            fp16 h = (fp16)f;
            hi[i + j] = h;
            lo[i + j] = (fp16)(f - (float)h);
        }
    }
}

// ------------- tiled transpose + cast: in fp32 [head][R][C] -> out fp16 [head][C][R] -------------
__global__ void transpose_cast(const float* __restrict__ in, fp16* __restrict__ out, int R, int C) {
    __shared__ float tile[64][65];
    const float* inh = in + (size_t)blockIdx.z * R * C;
    fp16* outh = out + (size_t)blockIdx.z * R * C;
    int r0 = blockIdx.x * 64, c0 = blockIdx.y * 64;
    int t = threadIdx.x;
#pragma unroll
    for (int i = 0; i < 16; i++) {
        int idx = i * 256 + t;
        int r = idx >> 6, c = idx & 63;
        tile[r][c] = inh[(size_t)(r0 + r) * C + c0 + c];
    }
    __syncthreads();
#pragma unroll
    for (int i = 0; i < 16; i++) {
        int idx = i * 256 + t;
        int cc = idx >> 6, rr = idx & 63;
        outh[(size_t)(c0 + cc) * R + r0 + rr] = (fp16)tile[rr][cc];
    }
}

// ---------------- QKV projection GEMM with fused RoPE epilogue ----------------
// C[s][c] = sum_k (xh+xl)[s][k] * w[head][c][k]   (w pre-transposed [head][64][2048])
// head < 32 -> rope -> qh/ql ; 32..39 -> rope -> kh/kl ; 40..47 -> vt[g][c][s]
__global__ __launch_bounds__(256) void gemm_qkv(
    const fp16* __restrict__ Ah, const fp16* __restrict__ Al, const fp16* __restrict__ Wt,
    fp16* __restrict__ qh, fp16* __restrict__ ql,
    fp16* __restrict__ kh, fp16* __restrict__ kl, fp16* __restrict__ vt) {
    __shared__ fp16 Ash[128][40];
    __shared__ fp16 Asl[128][40];
    __shared__ fp16 Bs[64][40];
    const int t = threadIdx.x;
    const int m0 = blockIdx.x * 128;
    const int head = blockIdx.z;
    const fp16* Bh = Wt + (size_t)head * HD * DIMM;
    const int wid = t >> 6, lane = t & 63;
    const int wm = (wid >> 1) * 64, wn = (wid & 1) * 32;
    const int lr = lane & 15, lg = lane >> 4;
    f32x4 acc[4][2] = {};
    for (int k0 = 0; k0 < DIMM; k0 += 32) {
#pragma unroll
        for (int c = 0; c < 2; c++) {
            int idx = c * 256 + t;
            int r = idx >> 2, col = (idx & 3) * 8;
            *reinterpret_cast<half8*>(&Ash[r][col]) =
                *reinterpret_cast<const half8*>(Ah + (size_t)(m0 + r) * DIMM + k0 + col);
            *reinterpret_cast<half8*>(&Asl[r][col]) =
                *reinterpret_cast<const half8*>(Al + (size_t)(m0 + r) * DIMM + k0 + col);
        }
        {
            int r = t >> 2, col = (t & 3) * 8;
            *reinterpret_cast<half8*>(&Bs[r][col]) =
                *reinterpret_cast<const half8*>(Bh + (size_t)r * DIMM + k0 + col);
        }
        __syncthreads();
        half8 ah[4], al[4], bf[2];
#pragma unroll
        for (int m = 0; m < 4; m++) {
            ah[m] = *reinterpret_cast<const half8*>(&Ash[wm + m * 16 + lr][lg * 8]);
            al[m] = *reinterpret_cast<const half8*>(&Asl[wm + m * 16 + lr][lg * 8]);
        }
#pragma unroll
        for (int n = 0; n < 2; n++)
            bf[n] = *reinterpret_cast<const half8*>(&Bs[wn + n * 16 + lr][lg * 8]);
#pragma unroll
        for (int m = 0; m < 4; m++)
#pragma unroll
            for (int n = 0; n < 2; n++) {
                acc[m][n] = __builtin_amdgcn_mfma_f32_16x16x32_f16(ah[m], bf[n], acc[m][n], 0, 0, 0);
                acc[m][n] = __builtin_amdgcn_mfma_f32_16x16x32_f16(al[m], bf[n], acc[m][n], 0, 0, 0);
            }
        __syncthreads();
    }
    if (head < 40) {
        // RoPE epilogue: col pairs (2j, 2j+1); partner value lives in lane^1.
        fp16* dh = (head < NQH) ? qh + (size_t)head * SEQ * HD : kh + (size_t)(head - NQH) * SEQ * HD;
        fp16* dl = (head < NQH) ? ql + (size_t)head * SEQ * HD : kl + (size_t)(head - NQH) * SEQ * HD;
#pragma unroll
        for (int m = 0; m < 4; m++)
#pragma unroll
            for (int n = 0; n < 2; n++)
#pragma unroll
                for (int r = 0; r < 4; r++) {
                    int row = m0 + wm + m * 16 + lg * 4 + r;  // seq position
                    int c = wn + n * 16 + lr;                 // head dim 0..63
                    float val = acc[m][n][r];
                    float pv = __shfl_xor(val, 1);            // partner column value
                    int j = c >> 1;
                    float invf = expf(-0.28782313662425572f * (float)j);  // 10000^(-j/32)
                    float ang = (float)row * invf;
                    float sn, cs;
                    sincosf(ang, &sn, &cs);
                    float o = (c & 1) ? (sn * pv + cs * val) : (cs * val - sn * pv);
                    fp16 h = (fp16)o;
                    size_t off = (size_t)row * HD + c;
                    dh[off] = h;
                    dl[off] = (fp16)(o - (float)h);
                }
    } else {
        fp16* vh = vt + (size_t)(head - 40) * HD * SEQ;  // [64][2048]
#pragma unroll
        for (int m = 0; m < 4; m++)
#pragma unroll
            for (int n = 0; n < 2; n++)
#pragma unroll
                for (int r = 0; r < 4; r++) {
                    int row = m0 + wm + m * 16 + lg * 4 + r;
                    int c = wn + n * 16 + lr;
                    vh[(size_t)c * SEQ + row] = (fp16)acc[m][n][r];
                }
    }
}

// ---------------- causal flash attention (split-fp16 QK^T) ----------------
// grid (32 qblocks, 32 heads), 256 thr = 4 independent waves; each wave owns 16 q rows.
__global__ __launch_bounds__(256) void attn_kernel(
    const fp16* __restrict__ qh_, const fp16* __restrict__ ql_,
    const fp16* __restrict__ kh_, const fp16* __restrict__ kl_,
    const fp16* __restrict__ vt, fp16* __restrict__ o_all) {
    __shared__ fp16 P[4][16][72];
    const int t = threadIdx.x, wid = t >> 6, lane = t & 63;
    const int head = blockIdx.y, g = head >> 2;
    const int qr0 = blockIdx.x * 64 + wid * 16;
    const int lr = lane & 15, lg = lane >> 4;
    const fp16* qhh = qh_ + (size_t)head * SEQ * HD;
    const fp16* qhl = ql_ + (size_t)head * SEQ * HD;
    const fp16* khh = kh_ + (size_t)g * SEQ * HD;
    const fp16* khl = kl_ + (size_t)g * SEQ * HD;
    const fp16* vh = vt + (size_t)g * HD * SEQ;
    half8 aq0h = *reinterpret_cast<const half8*>(qhh + (size_t)(qr0 + lr) * HD + lg * 8);
    half8 aq1h = *reinterpret_cast<const half8*>(qhh + (size_t)(qr0 + lr) * HD + 32 + lg * 8);
    half8 aq0l = *reinterpret_cast<const half8*>(qhl + (size_t)(qr0 + lr) * HD + lg * 8);
    half8 aq1l = *reinterpret_cast<const half8*>(qhl + (size_t)(qr0 + lr) * HD + 32 + lg * 8);
    f32x4 o[4] = {};
    float m[4], lsum[4];
#pragma unroll
    for (int r = 0; r < 4; r++) { m[r] = -1e30f; lsum[r] = 0.0f; }
    const int nt = (qr0 + 79) >> 6;
    const int fullT = (qr0 + 1) >> 6;
    for (int tile = 0; tile < nt; ++tile) {
        const int kv0 = tile << 6;
        f32x4 sc[4];
#pragma unroll
        for (int f = 0; f < 4; f++) {
            const size_t kro = (size_t)(kv0 + f * 16 + lr) * HD + lg * 8;
            half8 b0h = *reinterpret_cast<const half8*>(khh + kro);
            half8 b1h = *reinterpret_cast<const half8*>(khh + kro + 32);
            half8 b0l = *reinterpret_cast<const half8*>(khl + kro);
            half8 b1l = *reinterpret_cast<const half8*>(khl + kro + 32);
            f32x4 s = {};
            s = __builtin_amdgcn_mfma_f32_16x16x32_f16(aq0h, b0h, s, 0, 0, 0);
            s = __builtin_amdgcn_mfma_f32_16x16x32_f16(aq0h, b0l, s, 0, 0, 0);
            s = __builtin_amdgcn_mfma_f32_16x16x32_f16(aq0l, b0h, s, 0, 0, 0);
            s = __builtin_amdgcn_mfma_f32_16x16x32_f16(aq1h, b1h, s, 0, 0, 0);
            s = __builtin_amdgcn_mfma_f32_16x16x32_f16(aq1h, b1l, s, 0, 0, 0);
            s = __builtin_amdgcn_mfma_f32_16x16x32_f16(aq1l, b1h, s, 0, 0, 0);
            sc[f] = s * 0.125f;
        }
        if (tile >= fullT) {
#pragma unroll
            for (int f = 0; f < 4; f++)
#pragma unroll
                for (int r = 0; r < 4; r++) {
                    int q = qr0 + lg * 4 + r, kv = kv0 + f * 16 + lr;
                    if (kv > q) sc[f][r] = -1e30f;
                }
        }
        float alpha[4];
#pragma unroll
        for (int r = 0; r < 4; r++) {
            float v = fmaxf(fmaxf(sc[0][r], sc[1][r]), fmaxf(sc[2][r], sc[3][r]));
            v = fmaxf(v, __shfl_xor(v, 1));
            v = fmaxf(v, __shfl_xor(v, 2));
            v = fmaxf(v, __shfl_xor(v, 4));
            v = fmaxf(v, __shfl_xor(v, 8));
            float mn = fmaxf(m[r], v);
            alpha[r] = __expf(m[r] - mn);
            m[r] = mn;
        }
        float rs[4] = {0.f, 0.f, 0.f, 0.f};
#pragma unroll
        for (int f = 0; f < 4; f++)
#pragma unroll
            for (int r = 0; r < 4; r++) {
                float p = __expf(sc[f][r] - m[r]);
                sc[f][r] = p;
                rs[r] += p;
            }
#pragma unroll
        for (int r = 0; r < 4; r++) {
            float v = rs[r];
            v += __shfl_xor(v, 1);
            v += __shfl_xor(v, 2);
            v += __shfl_xor(v, 4);
            v += __shfl_xor(v, 8);
            lsum[r] = lsum[r] * alpha[r] + v;
        }
#pragma unroll
        for (int f = 0; f < 4; f++)
#pragma unroll
            for (int r = 0; r < 4; r++)
                P[wid][lg * 4 + r][f * 16 + lr] = (fp16)sc[f][r];
#pragma unroll
        for (int vf = 0; vf < 4; vf++)
#pragma unroll
            for (int r = 0; r < 4; r++) o[vf][r] *= alpha[r];
#pragma unroll
        for (int half = 0; half < 2; half++) {
            half8 pa = *reinterpret_cast<const half8*>(&P[wid][lr][half * 32 + lg * 8]);
#pragma unroll
            for (int vf = 0; vf < 4; vf++) {
                half8 bv = *reinterpret_cast<const half8*>(
                    vh + (size_t)(vf * 16 + lr) * SEQ + kv0 + half * 32 + lg * 8);
                o[vf] = __builtin_amdgcn_mfma_f32_16x16x32_f16(pa, bv, o[vf], 0, 0, 0);
            }
        }
    }
#pragma unroll
    for (int vf = 0; vf < 4; vf++)
#pragma unroll
        for (int r = 0; r < 4; r++) {
            float v = o[vf][r] / lsum[r];
            o_all[(size_t)(qr0 + lg * 4 + r) * 2048 + head * 64 + vf * 16 + lr] = (fp16)v;
        }
}

// ---------------- out projection: C[M][N] = A[M][K] * Bt[N][K]^T, fp16 in, fp32 out ----------------
__global__ __launch_bounds__(256) void gemm_out(
    const fp16* __restrict__ A, const fp16* __restrict__ Bt, float* __restrict__ Cout,
    int M, int N, int K) {
    __shared__ fp16 As[128][40];
    __shared__ fp16 Bs[64][40];
    const int t = threadIdx.x;
    const int m0 = blockIdx.x * 128;
    const int n0 = blockIdx.y * 64;
    const int wid = t >> 6, lane = t & 63;
    const int wm = (wid >> 1) * 64, wn = (wid & 1) * 32;
    const int lr = lane & 15, lg = lane >> 4;
    f32x4 acc[4][2] = {};
    for (int k0 = 0; k0 < K; k0 += 32) {
#pragma unroll
        for (int c = 0; c < 2; c++) {
            int idx = c * 256 + t;
            int r = idx >> 2, col = (idx & 3) * 8;
            *reinterpret_cast<half8*>(&As[r][col]) =
                *reinterpret_cast<const half8*>(A + (size_t)(m0 + r) * K + k0 + col);
        }
        {
            int r = t >> 2, col = (t & 3) * 8;
            *reinterpret_cast<half8*>(&Bs[r][col]) =
                *reinterpret_cast<const half8*>(Bt + (size_t)(n0 + r) * K + k0 + col);
        }
        __syncthreads();
        half8 af[4], bfr[2];
#pragma unroll
        for (int m = 0; m < 4; m++)
            af[m] = *reinterpret_cast<const half8*>(&As[wm + m * 16 + lr][lg * 8]);
#pragma unroll
        for (int n = 0; n < 2; n++)
            bfr[n] = *reinterpret_cast<const half8*>(&Bs[wn + n * 16 + lr][lg * 8]);
#pragma unroll
        for (int m = 0; m < 4; m++)
#pragma unroll
            for (int n = 0; n < 2; n++)
                acc[m][n] = __builtin_amdgcn_mfma_f32_16x16x32_f16(af[m], bfr[n], acc[m][n], 0, 0, 0);
        __syncthreads();
    }
#pragma unroll
    for (int m = 0; m < 4; m++)
#pragma unroll
        for (int n = 0; n < 2; n++)
#pragma unroll
            for (int r = 0; r < 4; r++) {
                int row = m0 + wm + m * 16 + lg * 4 + r;
                int col = n0 + wn + n * 16 + lr;
                Cout[(size_t)row * N + col] = acc[m][n][r];
            }
}

extern "C" void kernel_launch(void* const* d_in, const int* in_sizes, int n_in,
                              void* d_out, int out_size, void* d_ws, size_t ws_size,
                              hipStream_t stream) {
    const float* x  = (const float*)d_in[0];
    const float* wq = (const float*)d_in[1];  // [8][4][2048][64] = [32][2048][64]
    const float* wk = (const float*)d_in[2];  // [8][2048][64]
    const float* wv = (const float*)d_in[3];  // [8][2048][64]
    const float* wo = (const float*)d_in[4];  // [8][4][64][2048] = [2048 hv][2048 d]
    float* out = (float*)d_out;
    char* ws = (char*)d_ws;

    // Workspace (50 MB peak, aliased regions noted):
    fp16* xh    = (fp16*)(ws);                        // 8 MB  [2048][2048]  (dead after gemm_qkv)
    fp16* w2t   = xh;                                 //       alias: [2048 d][2048 hv]
    fp16* xl    = (fp16*)(ws + ((size_t)8 << 20));    // 8 MB  (dead after gemm_qkv)
    fp16* o_all = xl;                                 //       alias: [2048][2048]
    fp16* wqkvt = (fp16*)(ws + ((size_t)16 << 20));   // 12 MB [48][64][2048]
    fp16* qh    = (fp16*)(ws + ((size_t)28 << 20));   // 8 MB  [32][2048][64]
    fp16* ql    = (fp16*)(ws + ((size_t)36 << 20));   // 8 MB
    fp16* kh    = (fp16*)(ws + ((size_t)44 << 20));   // 2 MB  [8][2048][64]
    fp16* kl    = (fp16*)(ws + ((size_t)46 << 20));   // 2 MB
    fp16* vtb   = (fp16*)(ws + ((size_t)48 << 20));   // 2 MB  [8][64][2048]

    // 1. split x; transpose weights to [head][64][2048] fp16
    split_f32_f16<<<dim3(4096), 256, 0, stream>>>(x, xh, xl, SEQ * DIMM);
    transpose_cast<<<dim3(32, 1, 32), 256, 0, stream>>>(wq, wqkvt, 2048, 64);
    transpose_cast<<<dim3(32, 1, 8), 256, 0, stream>>>(wk, wqkvt + (size_t)32 * 64 * 2048, 2048, 64);
    transpose_cast<<<dim3(32, 1, 8), 256, 0, stream>>>(wv, wqkvt + (size_t)40 * 64 * 2048, 2048, 64);
    // 2. QKV projection (2-term split-A) with fused RoPE/split epilogue
    gemm_qkv<<<dim3(16, 1, 48), 256, 0, stream>>>(xh, xl, wqkvt, qh, ql, kh, kl, vtb);
    // 3. w_out transpose (reuses xh region, now dead)
    transpose_cast<<<dim3(32, 32, 1), 256, 0, stream>>>(wo, w2t, 2048, 2048);
    // 4. attention (3-term split QK^T)
    attn_kernel<<<dim3(32, 32), 256, 0, stream>>>(qh, ql, kh, kl, vtb, o_all);
    // 5. out projection -> fp32 d_out
    gemm_out<<<dim3(16, 32), 256, 0, stream>>>(o_all, w2t, out, 2048, 2048, 2048);
}

// Round 4
// 232.198 us; speedup vs baseline: 2.1069x; 2.1069x over previous
//
#include <hip/hip_runtime.h>
#include <hip/hip_bf16.h>

#define SEQ 2048
#define DIMM 2048
#define NQH 32
#define NKVH 8
#define HD 64

typedef _Float16 half8 __attribute__((ext_vector_type(8)));
typedef float f32x4 __attribute__((ext_vector_type(4)));
using fp16 = _Float16;

typedef __attribute__((address_space(1))) unsigned int ga_u32;
typedef __attribute__((address_space(3))) unsigned int ls_u32;

__device__ __forceinline__ void gll16(const void* g, void* l) {
    __builtin_amdgcn_global_load_lds((const ga_u32*)g, (ls_u32*)l, 16, 0, 0);
}

// ---------------- split fp32 -> fp16 hi + fp16 lo (vectorized) ----------------
__global__ void split_f32_f16(const float* __restrict__ in, fp16* __restrict__ hi,
                              fp16* __restrict__ lo, int n) {
    int i = (blockIdx.x * 256 + threadIdx.x) * 4;
    if (i < n) {
        float4 v = *reinterpret_cast<const float4*>(in + i);
#pragma unroll
        for (int j = 0; j < 4; j++) {
            float f = (&v.x)[j];
            fp16 h = (fp16)f;
            hi[i + j] = h;
            lo[i + j] = (fp16)(f - (float)h);
        }
    }
}

// ------------- tiled transpose + cast: in fp32 [head][R][C] -> out fp16 [head][C][R] -------------
__global__ void transpose_cast(const float* __restrict__ in, fp16* __restrict__ out, int R, int C) {
    __shared__ float tile[64][65];
    const float* inh = in + (size_t)blockIdx.z * R * C;
    fp16* outh = out + (size_t)blockIdx.z * R * C;
    int r0 = blockIdx.x * 64, c0 = blockIdx.y * 64;
    int t = threadIdx.x;
#pragma unroll
    for (int i = 0; i < 16; i++) {
        int idx = i * 256 + t;
        int r = idx >> 6, c = idx & 63;
        tile[r][c] = inh[(size_t)(r0 + r) * C + c0 + c];
    }
    __syncthreads();
#pragma unroll
    for (int i = 0; i < 16; i++) {
        int idx = i * 256 + t;
        int cc = idx >> 6, rr = idx & 63;
        outh[(size_t)(c0 + cc) * R + r0 + rr] = (fp16)tile[rr][cc];
    }
}

// ---------------- QKV projection GEMM with fused RoPE epilogue ----------------
__global__ __launch_bounds__(256) void gemm_qkv(
    const fp16* __restrict__ Ah, const fp16* __restrict__ Al, const fp16* __restrict__ Wt,
    fp16* __restrict__ qh, fp16* __restrict__ ql,
    fp16* __restrict__ kh, fp16* __restrict__ kl, fp16* __restrict__ vt) {
    __shared__ fp16 Ash[128][40];
    __shared__ fp16 Asl[128][40];
    __shared__ fp16 Bs[64][40];
    const int t = threadIdx.x;
    const int m0 = blockIdx.x * 128;
    const int head = blockIdx.z;
    const fp16* Bh = Wt + (size_t)head * HD * DIMM;
    const int wid = t >> 6, lane = t & 63;
    const int wm = (wid >> 1) * 64, wn = (wid & 1) * 32;
    const int lr = lane & 15, lg = lane >> 4;
    f32x4 acc[4][2] = {};
    for (int k0 = 0; k0 < DIMM; k0 += 32) {
#pragma unroll
        for (int c = 0; c < 2; c++) {
            int idx = c * 256 + t;
            int r = idx >> 2, col = (idx & 3) * 8;
            *reinterpret_cast<half8*>(&Ash[r][col]) =
                *reinterpret_cast<const half8*>(Ah + (size_t)(m0 + r) * DIMM + k0 + col);
            *reinterpret_cast<half8*>(&Asl[r][col]) =
                *reinterpret_cast<const half8*>(Al + (size_t)(m0 + r) * DIMM + k0 + col);
        }
        {
            int r = t >> 2, col = (t & 3) * 8;
            *reinterpret_cast<half8*>(&Bs[r][col]) =
                *reinterpret_cast<const half8*>(Bh + (size_t)r * DIMM + k0 + col);
        }
        __syncthreads();
        half8 ah[4], al[4], bf[2];
#pragma unroll
        for (int m = 0; m < 4; m++) {
            ah[m] = *reinterpret_cast<const half8*>(&Ash[wm + m * 16 + lr][lg * 8]);
            al[m] = *reinterpret_cast<const half8*>(&Asl[wm + m * 16 + lr][lg * 8]);
        }
#pragma unroll
        for (int n = 0; n < 2; n++)
            bf[n] = *reinterpret_cast<const half8*>(&Bs[wn + n * 16 + lr][lg * 8]);
#pragma unroll
        for (int m = 0; m < 4; m++)
#pragma unroll
            for (int n = 0; n < 2; n++) {
                acc[m][n] = __builtin_amdgcn_mfma_f32_16x16x32_f16(ah[m], bf[n], acc[m][n], 0, 0, 0);
                acc[m][n] = __builtin_amdgcn_mfma_f32_16x16x32_f16(al[m], bf[n], acc[m][n], 0, 0, 0);
            }
        __syncthreads();
    }
    if (head < 40) {
        fp16* dh = (head < NQH) ? qh + (size_t)head * SEQ * HD : kh + (size_t)(head - NQH) * SEQ * HD;
        fp16* dl = (head < NQH) ? ql + (size_t)head * SEQ * HD : kl + (size_t)(head - NQH) * SEQ * HD;
#pragma unroll
        for (int m = 0; m < 4; m++)
#pragma unroll
            for (int n = 0; n < 2; n++)
#pragma unroll
                for (int r = 0; r < 4; r++) {
                    int row = m0 + wm + m * 16 + lg * 4 + r;
                    int c = wn + n * 16 + lr;
                    float val = acc[m][n][r];
                    float pv = __shfl_xor(val, 1);
                    int j = c >> 1;
                    float invf = expf(-0.28782313662425572f * (float)j);
                    float ang = (float)row * invf;
                    float sn, cs;
                    sincosf(ang, &sn, &cs);
                    float o = (c & 1) ? (sn * pv + cs * val) : (cs * val - sn * pv);
                    fp16 h = (fp16)o;
                    size_t off = (size_t)row * HD + c;
                    dh[off] = h;
                    dl[off] = (fp16)(o - (float)h);
                }
    } else {
        fp16* vh = vt + (size_t)(head - 40) * HD * SEQ;
#pragma unroll
        for (int m = 0; m < 4; m++)
#pragma unroll
            for (int n = 0; n < 2; n++)
#pragma unroll
                for (int r = 0; r < 4; r++) {
                    int row = m0 + wm + m * 16 + lg * 4 + r;
                    int c = wn + n * 16 + lr;
                    vh[(size_t)c * SEQ + row] = (fp16)acc[m][n][r];
                }
    }
}

// ---------------- causal flash attention (split-fp16 QK^T, LDS double-buffered K/V) ----------------
// grid (16 qpairs, 32 heads), 256 thr = 4 waves; block processes q-tile p then 31-p (33 kv-tiles).
__global__ __launch_bounds__(256) void attn_kernel(
    const fp16* __restrict__ qh_, const fp16* __restrict__ ql_,
    const fp16* __restrict__ kh_, const fp16* __restrict__ kl_,
    const fp16* __restrict__ vt, fp16* __restrict__ o_all) {
    __shared__ fp16 Kb[2][2][64][64];  // [buf][hi/lo][kv row][dim]  (16B-chunk XOR swizzled)
    __shared__ fp16 Vb[2][64][64];     // [buf][dim][kv-local]       (swizzled)
    __shared__ fp16 P[4][16][72];
    const int t = threadIdx.x, wid = t >> 6, lane = t & 63;
    const int head = blockIdx.y, g = head >> 2;
    const int lr = lane & 15, lg = lane >> 4;
    const fp16* qhh = qh_ + (size_t)head * SEQ * HD;
    const fp16* qhl = ql_ + (size_t)head * SEQ * HD;
    const fp16* khh = kh_ + (size_t)g * SEQ * HD;
    const fp16* khl = kl_ + (size_t)g * SEQ * HD;
    const fp16* vh = vt + (size_t)g * HD * SEQ;
    const int srow = lane >> 3;   // 0..7
    const int schunk = lane & 7;  // 16B chunk 0..7

    for (int pass = 0; pass < 2; ++pass) {
        const int qt = (pass == 0) ? (int)blockIdx.x : 31 - (int)blockIdx.x;
        const int qr0 = qt * 64 + wid * 16;
        half8 aq0h = *reinterpret_cast<const half8*>(qhh + (size_t)(qr0 + lr) * HD + lg * 8);
        half8 aq1h = *reinterpret_cast<const half8*>(qhh + (size_t)(qr0 + lr) * HD + 32 + lg * 8);
        half8 aq0l = *reinterpret_cast<const half8*>(qhl + (size_t)(qr0 + lr) * HD + lg * 8);
        half8 aq1l = *reinterpret_cast<const half8*>(qhl + (size_t)(qr0 + lr) * HD + 32 + lg * 8);
        f32x4 o[4] = {};
        float m[4], lsum[4];
#pragma unroll
        for (int r = 0; r < 4; r++) { m[r] = -1e30f; lsum[r] = 0.0f; }
        const int nt = qt + 1;

        // cooperative stage of kv-tile kt into buffer b (6 x 16B gll per wave)
        auto stage = [&](int kt, int b) {
            const int kv0 = kt << 6;
#pragma unroll
            for (int i = 0; i < 2; ++i) {
                int row = wid * 16 + i * 8 + srow;            // local kv row / dim row
                int sw = (schunk ^ srow) * 8;                 // swizzled element offset
                gll16(khh + (size_t)(kv0 + row) * HD + sw, &Kb[b][0][wid * 16 + i * 8][0]);
                gll16(khl + (size_t)(kv0 + row) * HD + sw, &Kb[b][1][wid * 16 + i * 8][0]);
                gll16(vh + (size_t)row * SEQ + kv0 + sw, &Vb[b][wid * 16 + i * 8][0]);
            }
        };

        stage(0, 0);
        __syncthreads();
        for (int tt = 0; tt < nt; ++tt) {
            const int cur = tt & 1;
            if (tt + 1 < nt) stage(tt + 1, cur ^ 1);
            const int kv0 = tt << 6;
            f32x4 sc[4];
            __builtin_amdgcn_s_setprio(1);
#pragma unroll
            for (int f = 0; f < 4; ++f) {
                int row = f * 16 + lr;
                const char* kb0 = (const char*)&Kb[cur][0][row][0];
                const char* kb1 = (const char*)&Kb[cur][1][row][0];
                int x0 = ((lg) ^ (row & 7)) * 16;
                int x1 = ((4 + lg) ^ (row & 7)) * 16;
                half8 b0h = *(const half8*)(kb0 + x0);
                half8 b1h = *(const half8*)(kb0 + x1);
                half8 b0l = *(const half8*)(kb1 + x0);
                half8 b1l = *(const half8*)(kb1 + x1);
                f32x4 s = {};
                s = __builtin_amdgcn_mfma_f32_16x16x32_f16(aq0h, b0h, s, 0, 0, 0);
                s = __builtin_amdgcn_mfma_f32_16x16x32_f16(aq0h, b0l, s, 0, 0, 0);
                s = __builtin_amdgcn_mfma_f32_16x16x32_f16(aq0l, b0h, s, 0, 0, 0);
                s = __builtin_amdgcn_mfma_f32_16x16x32_f16(aq1h, b1h, s, 0, 0, 0);
                s = __builtin_amdgcn_mfma_f32_16x16x32_f16(aq1h, b1l, s, 0, 0, 0);
                s = __builtin_amdgcn_mfma_f32_16x16x32_f16(aq1l, b1h, s, 0, 0, 0);
                sc[f] = s * 0.125f;
            }
            __builtin_amdgcn_s_setprio(0);
            if (tt == qt) {
#pragma unroll
                for (int f = 0; f < 4; f++)
#pragma unroll
                    for (int r = 0; r < 4; r++) {
                        int q = qr0 + lg * 4 + r, kv = kv0 + f * 16 + lr;
                        if (kv > q) sc[f][r] = -1e30f;
                    }
            }
            float alpha[4];
#pragma unroll
            for (int r = 0; r < 4; r++) {
                float v = fmaxf(fmaxf(sc[0][r], sc[1][r]), fmaxf(sc[2][r], sc[3][r]));
                v = fmaxf(v, __shfl_xor(v, 1));
                v = fmaxf(v, __shfl_xor(v, 2));
                v = fmaxf(v, __shfl_xor(v, 4));
                v = fmaxf(v, __shfl_xor(v, 8));
                float mn = fmaxf(m[r], v);
                alpha[r] = __expf(m[r] - mn);
                m[r] = mn;
            }
            float rs[4] = {0.f, 0.f, 0.f, 0.f};
#pragma unroll
            for (int f = 0; f < 4; f++)
#pragma unroll
                for (int r = 0; r < 4; r++) {
                    float p = __expf(sc[f][r] - m[r]);
                    sc[f][r] = p;
                    rs[r] += p;
                }
#pragma unroll
            for (int r = 0; r < 4; r++) {
                float v = rs[r];
                v += __shfl_xor(v, 1);
                v += __shfl_xor(v, 2);
                v += __shfl_xor(v, 4);
                v += __shfl_xor(v, 8);
                lsum[r] = lsum[r] * alpha[r] + v;
            }
#pragma unroll
            for (int f = 0; f < 4; f++)
#pragma unroll
                for (int r = 0; r < 4; r++)
                    P[wid][lg * 4 + r][f * 16 + lr] = (fp16)sc[f][r];
#pragma unroll
            for (int vf = 0; vf < 4; vf++)
#pragma unroll
                for (int r = 0; r < 4; r++) o[vf][r] *= alpha[r];
            __builtin_amdgcn_s_setprio(1);
#pragma unroll
            for (int half = 0; half < 2; half++) {
                half8 pa = *reinterpret_cast<const half8*>(&P[wid][lr][half * 32 + lg * 8]);
#pragma unroll
                for (int vf = 0; vf < 4; vf++) {
                    int d = vf * 16 + lr;
                    int xo = ((half * 4 + lg) ^ (d & 7)) * 16;
                    half8 bv = *(const half8*)((const char*)&Vb[cur][d][0] + xo);
                    o[vf] = __builtin_amdgcn_mfma_f32_16x16x32_f16(pa, bv, o[vf], 0, 0, 0);
                }
            }
            __builtin_amdgcn_s_setprio(0);
            __syncthreads();  // drains vmcnt (stage of tt+1) + protects buffer reuse
        }
#pragma unroll
        for (int vf = 0; vf < 4; vf++)
#pragma unroll
            for (int r = 0; r < 4; r++) {
                float v = o[vf][r] / lsum[r];
                o_all[(size_t)(qr0 + lg * 4 + r) * 2048 + head * 64 + vf * 16 + lr] = (fp16)v;
            }
        __syncthreads();  // pass boundary: all reads of bufs done before next pass restages
    }
}

// ---------------- out projection: C[M][N] = A[M][K] * Bt[N][K]^T, fp16 in, fp32 out ----------------
__global__ __launch_bounds__(256) void gemm_out(
    const fp16* __restrict__ A, const fp16* __restrict__ Bt, float* __restrict__ Cout,
    int M, int N, int K) {
    __shared__ fp16 As[128][40];
    __shared__ fp16 Bs[64][40];
    const int t = threadIdx.x;
    const int m0 = blockIdx.x * 128;
    const int n0 = blockIdx.y * 64;
    const int wid = t >> 6, lane = t & 63;
    const int wm = (wid >> 1) * 64, wn = (wid & 1) * 32;
    const int lr = lane & 15, lg = lane >> 4;
    f32x4 acc[4][2] = {};
    for (int k0 = 0; k0 < K; k0 += 32) {
#pragma unroll
        for (int c = 0; c < 2; c++) {
            int idx = c * 256 + t;
            int r = idx >> 2, col = (idx & 3) * 8;
            *reinterpret_cast<half8*>(&As[r][col]) =
                *reinterpret_cast<const half8*>(A + (size_t)(m0 + r) * K + k0 + col);
        }
        {
            int r = t >> 2, col = (t & 3) * 8;
            *reinterpret_cast<half8*>(&Bs[r][col]) =
                *reinterpret_cast<const half8*>(Bt + (size_t)(n0 + r) * K + k0 + col);
        }
        __syncthreads();
        half8 af[4], bfr[2];
#pragma unroll
        for (int m = 0; m < 4; m++)
            af[m] = *reinterpret_cast<const half8*>(&As[wm + m * 16 + lr][lg * 8]);
#pragma unroll
        for (int n = 0; n < 2; n++)
            bfr[n] = *reinterpret_cast<const half8*>(&Bs[wn + n * 16 + lr][lg * 8]);
#pragma unroll
        for (int m = 0; m < 4; m++)
#pragma unroll
            for (int n = 0; n < 2; n++)
                acc[m][n] = __builtin_amdgcn_mfma_f32_16x16x32_f16(af[m], bfr[n], acc[m][n], 0, 0, 0);
        __syncthreads();
    }
#pragma unroll
    for (int m = 0; m < 4; m++)
#pragma unroll
        for (int n = 0; n < 2; n++)
#pragma unroll
            for (int r = 0; r < 4; r++) {
                int row = m0 + wm + m * 16 + lg * 4 + r;
                int col = n0 + wn + n * 16 + lr;
                Cout[(size_t)row * N + col] = acc[m][n][r];
            }
}

extern "C" void kernel_launch(void* const* d_in, const int* in_sizes, int n_in,
                              void* d_out, int out_size, void* d_ws, size_t ws_size,
                              hipStream_t stream) {
    const float* x  = (const float*)d_in[0];
    const float* wq = (const float*)d_in[1];
    const float* wk = (const float*)d_in[2];
    const float* wv = (const float*)d_in[3];
    const float* wo = (const float*)d_in[4];
    float* out = (float*)d_out;
    char* ws = (char*)d_ws;

    fp16* xh    = (fp16*)(ws);                        // 8 MB (dead after gemm_qkv)
    fp16* w2t   = xh;                                 // alias
    fp16* xl    = (fp16*)(ws + ((size_t)8 << 20));    // 8 MB (dead after gemm_qkv)
    fp16* o_all = xl;                                 // alias
    fp16* wqkvt = (fp16*)(ws + ((size_t)16 << 20));   // 12 MB
    fp16* qh    = (fp16*)(ws + ((size_t)28 << 20));   // 8 MB
    fp16* ql    = (fp16*)(ws + ((size_t)36 << 20));   // 8 MB
    fp16* kh    = (fp16*)(ws + ((size_t)44 << 20));   // 2 MB
    fp16* kl    = (fp16*)(ws + ((size_t)46 << 20));   // 2 MB
    fp16* vtb   = (fp16*)(ws + ((size_t)48 << 20));   // 2 MB

    split_f32_f16<<<dim3(4096), 256, 0, stream>>>(x, xh, xl, SEQ * DIMM);
    transpose_cast<<<dim3(32, 1, 32), 256, 0, stream>>>(wq, wqkvt, 2048, 64);
    transpose_cast<<<dim3(32, 1, 8), 256, 0, stream>>>(wk, wqkvt + (size_t)32 * 64 * 2048, 2048, 64);
    transpose_cast<<<dim3(32, 1, 8), 256, 0, stream>>>(wv, wqkvt + (size_t)40 * 64 * 2048, 2048, 64);
    gemm_qkv<<<dim3(16, 1, 48), 256, 0, stream>>>(xh, xl, wqkvt, qh, ql, kh, kl, vtb);
    transpose_cast<<<dim3(32, 32, 1), 256, 0, stream>>>(wo, w2t, 2048, 2048);
    attn_kernel<<<dim3(16, 32), 256, 0, stream>>>(qh, ql, kh, kl, vtb, o_all);
    gemm_out<<<dim3(16, 32), 256, 0, stream>>>(o_all, w2t, out, 2048, 2048, 2048);
}